// Round 1
// baseline (3198.297 us; speedup 1.0000x reference)
//
#include <hip/hip_runtime.h>

typedef _Float16 f16;
typedef f16 f16x4 __attribute__((ext_vector_type(4)));
typedef f16 f16x8 __attribute__((ext_vector_type(8)));
typedef float f32x4 __attribute__((ext_vector_type(4)));

#define NTOK 8192
#define DDIM 256
#define MKEY 16384
#define TOPK 32
#define CH   64
#define NCH  128   // 8192 keys per half / 64

// ---------------- prep: f32 -> fp16 conversions ----------------
__global__ __launch_bounds__(256) void prep_cvt(const float* __restrict__ x,
                                                const float* __restrict__ mk,
                                                f16* __restrict__ xh, f16* __restrict__ kh)
{
  int i = blockIdx.x * 256 + threadIdx.x;
  const int NX4 = NTOK * DDIM / 4;
  if (i < NX4) {
    float4 v = ((const float4*)x)[i];
    f16x4 o = {(f16)v.x, (f16)v.y, (f16)v.z, (f16)v.w};
    ((f16x4*)xh)[i] = o;
  } else {
    int j = i - NX4;                       // < MKEY*DDIM/4
    float4 v = ((const float4*)mk)[j];
    f16x4 o = {(f16)v.x, (f16)v.y, (f16)v.z, (f16)v.w};
    ((f16x4*)kh)[j] = o;
  }
}

// transpose W [k][n] -> WT [n][k] in fp16 (both 256x256)
__global__ __launch_bounds__(256) void prep_tr(const float* __restrict__ Wf,
                                               const float* __restrict__ Wo,
                                               f16* __restrict__ WfT, f16* __restrict__ WoT)
{
  int i = blockIdx.x * 256 + threadIdx.x;  // 0..131071
  const float* W = Wf; f16* WT = WfT; int j = i;
  if (i >= 65536) { W = Wo; WT = WoT; j = i - 65536; }
  int n = j >> 8, k = j & 255;
  WT[j] = (f16)W[k * 256 + n];
}

// ---------------- K1: scores (MFMA fp16) + streaming top-32 ----------------
// grid 256: 128 token-blocks (64 tokens) x 2 key-halves (8192 keys each)
__global__ __launch_bounds__(256) void k1_topk(const f16* __restrict__ xh,
                                               const f16* __restrict__ kh,
                                               float* __restrict__ pt_s,
                                               int* __restrict__ pt_i)
{
  __shared__ __align__(16) f16 kbuf[2][CH * DDIM];   // 64 KB, XOR-swizzled
  __shared__ float sc[4][CH][17];                    // per-wave scores [key][token]
  __shared__ float tks[64][TOPK];
  __shared__ int   tki[64][TOPK];
  __shared__ float tkmin[64];
  __shared__ int   tkmp[64];

  const int tid = threadIdx.x, lane = tid & 63, wv = tid >> 6;
  // XCD swizzle: 32 consecutive swz per XCD; half = swz>>7 so XCDs 0-3 own half 0
  // (one 4MB fp16 key-half per XCD group -> L2-resident sweep)
  int swz = (blockIdx.x & 7) * 32 + (blockIdx.x >> 3);
  const int half = swz >> 7;
  const int tb   = swz & 127;
  const int t0   = tb * 64;
  const int key0 = half * 8192;

  for (int i = tid; i < 64 * TOPK; i += 256) tks[i >> 5][i & 31] = -__builtin_inff();
  if (tid < 64) { tkmin[tid] = -__builtin_inff(); tkmp[tid] = 0; }

  // A fragments: wave's 16 tokens x 256 d, held in regs all kernel (32 VGPR)
  f16x8 afr[8];
  {
    const f16* ap = xh + (t0 + wv * 16 + (lane & 15)) * DDIM + (lane >> 4) * 8;
#pragma unroll
    for (int ks = 0; ks < 8; ++ks) afr[ks] = *(const f16x8*)(ap + ks * 32);
  }

  // stage one 64-key chunk into kbuf[buf]; LDS dest linear, global source
  // pre-swizzled so that lds[key*512 + (2d ^ ((key&7)<<4))] = kh[key][d]
  auto stage = [&](int buf, int c0) {
    const f16* base = kh + (key0 + c0) * DDIM;
#pragma unroll
    for (int is = 0; is < 8; ++is) {
      int o   = is * 4096 + wv * 1024 + lane * 16;   // linear byte offset in chunk
      int key = o >> 9;
      int d2  = (o & 511) ^ ((key & 7) << 4);        // byte offset of source d
      const void* g = (const char*)(base + key * DDIM) + d2;
      void* l = (char*)(&kbuf[buf][0]) + is * 4096 + wv * 1024;  // wave-uniform
      __builtin_amdgcn_global_load_lds((const __attribute__((address_space(1))) unsigned int*)g,
                                       (__attribute__((address_space(3))) unsigned int*)l,
                                       16, 0, 0);
    }
  };

  stage(0, 0);
  __syncthreads();

  const int tloc = wv * 16 + (lane >> 2);   // selection: 4 lanes per token
  const int q    = lane & 3;
  const int myk  = lane & 15;
  const int dgrp = (lane >> 4) * 8;

  for (int c = 0; c < NCH; ++c) {
    const int buf = c & 1;
    if (c + 1 < NCH) stage(buf ^ 1, (c + 1) * CH);   // async prefetch

    // ---- MFMA: 16 tokens x 64 keys, K=256 ----
    f32x4 acc[4];
#pragma unroll
    for (int kt = 0; kt < 4; ++kt) acc[kt] = (f32x4){0.f, 0.f, 0.f, 0.f};
    const char* kb = (const char*)&kbuf[buf][0];
#pragma unroll
    for (int ks = 0; ks < 8; ++ks) {
#pragma unroll
      for (int kt = 0; kt < 4; ++kt) {
        int key  = kt * 16 + myk;
        int addr = key * 512 + (((ks * 32 + dgrp) * 2) ^ ((key & 7) << 4));
        f16x8 b = *(const f16x8*)(kb + addr);
        acc[kt] = __builtin_amdgcn_mfma_f32_16x16x32_f16(afr[ks], b, acc[kt], 0, 0, 0);
      }
    }
    // write scores transposed: sc[wv][key][token]
#pragma unroll
    for (int kt = 0; kt < 4; ++kt) {
#pragma unroll
      for (int r = 0; r < 4; ++r)
        sc[wv][kt * 16 + myk][(lane >> 4) * 4 + r] = acc[kt][r];
    }
    asm volatile("s_waitcnt lgkmcnt(0)" ::: "memory");
    __builtin_amdgcn_sched_barrier(0);

    // ---- selection (wave-local; tokens owned exclusively per wave) ----
    {
      float thr = tkmin[tloc];
#pragma unroll 1
      for (int i2 = 0; i2 < 16; ++i2) {
        int k  = q * 16 + i2;
        float s = sc[wv][k][lane >> 2];
        bool cand = s > thr;
        if (__ballot(cand)) {
#pragma unroll 1
          for (int g = 0; g < 4; ++g) {           // serialize within 4-lane group
            if (q == g && cand) {
              float mn = tkmin[tloc];
              if (s > mn) {
                int p = tkmp[tloc];
                tks[tloc][p] = s;
                tki[tloc][p] = key0 + c * CH + k;
                float m = tks[tloc][0]; int mp = 0;
#pragma unroll 1
                for (int j = 1; j < TOPK; ++j) { float v = tks[tloc][j]; if (v < m) { m = v; mp = j; } }
                tkmin[tloc] = m; tkmp[tloc] = mp;
              }
            }
          }
          thr = tkmin[tloc];
        }
      }
    }
    __syncthreads();   // drains staging vmcnt + guards kbuf swap
  }

  // write partial top-32 per token
  for (int i = tid; i < 64 * TOPK; i += 256) {
    int tl = i >> 5, j = i & 31;
    int tok = t0 + tl;
    pt_s[tok * 64 + half * 32 + j] = tks[tl][j];
    pt_i[tok * 64 + half * 32 + j] = tki[tl][j];
  }
}

// ---------------- K2: merge halves, softmax, gather, fused = x + ctx ----------------
__global__ __launch_bounds__(256) void k2_merge(const float* __restrict__ pt_s,
                                                const int* __restrict__ pt_i,
                                                const float* __restrict__ x,
                                                const float* __restrict__ mv,
                                                float* __restrict__ fused)
{
  const int lane = threadIdx.x & 63, wv = threadIdx.x >> 6;
  const int tok = blockIdx.x * 4 + wv;
  float s = pt_s[tok * 64 + lane];
  int  id = pt_i[tok * 64 + lane];
  int rank = 0;
#pragma unroll 1
  for (int j = 0; j < 64; ++j) {
    float vj = __shfl(s, j);
    rank += (vj > s) || (vj == s && j < lane);
  }
  const bool keep = rank < TOPK;
  float m = keep ? s : -__builtin_inff();
#pragma unroll
  for (int o = 32; o; o >>= 1) m = fmaxf(m, __shfl_xor(m, o));
  float e = keep ? __expf(s - m) : 0.f;
  float sum = e;
#pragma unroll
  for (int o = 32; o; o >>= 1) sum += __shfl_xor(sum, o);
  float w = e / sum;

  const int d = lane * 4;
  float4 a = {0.f, 0.f, 0.f, 0.f};
#pragma unroll 1
  for (int j = 0; j < 64; ++j) {
    float wj = __shfl(w, j);
    int   ij = __shfl(id, j);
    if (wj != 0.f) {                              // uniform branch
      float4 v = *(const float4*)(mv + ij * 256 + d);
      a.x += wj * v.x; a.y += wj * v.y; a.z += wj * v.z; a.w += wj * v.w;
    }
  }
  float4 xv = *(const float4*)(x + tok * 256 + d);
  float4 o4 = {xv.x + a.x, xv.y + a.y, xv.z + a.z, xv.w + a.w};
  *(float4*)(fused + tok * 256 + d) = o4;
}

// ---------------- K3: fused GEMM1 -> LN -> ReLU -> GEMM2 ----------------
// 32 tokens per WG (2 waves x 16). Reads fused from d_out, writes out to d_out.
__global__ __launch_bounds__(128) void k3_ffn(const float* __restrict__ fused,
                                              const f16* __restrict__ WfT,
                                              const f16* __restrict__ WoT,
                                              const float* __restrict__ bf,
                                              const float* __restrict__ lg,
                                              const float* __restrict__ lb,
                                              const float* __restrict__ bo,
                                              float* __restrict__ out)
{
  __shared__ __align__(16) f16 hbuf[32 * DDIM];   // 16 KB, XOR-swizzled
  const int lane = threadIdx.x & 63, wv = threadIdx.x >> 6;
  const int t0 = blockIdx.x * 32;
  const int myr = lane & 15;
  const int dgrp = (lane >> 4) * 8;

  // A frags for GEMM1 (fused f32 -> fp16); fully loaded before any out write
  f16x8 a1[8];
  {
    const float* ap = fused + (t0 + wv * 16 + myr) * DDIM + dgrp;
#pragma unroll
    for (int ks = 0; ks < 8; ++ks) {
      float4 v0 = *(const float4*)(ap + ks * 32);
      float4 v1 = *(const float4*)(ap + ks * 32 + 4);
      f16x8 t = {(f16)v0.x, (f16)v0.y, (f16)v0.z, (f16)v0.w,
                 (f16)v1.x, (f16)v1.y, (f16)v1.z, (f16)v1.w};
      a1[ks] = t;
    }
  }
  f32x4 acc[16];
#pragma unroll
  for (int nt = 0; nt < 16; ++nt) acc[nt] = (f32x4){0.f, 0.f, 0.f, 0.f};
#pragma unroll 1
  for (int nt = 0; nt < 16; ++nt) {
    const f16* bp = WfT + (nt * 16 + myr) * DDIM + dgrp;
#pragma unroll
    for (int ks = 0; ks < 8; ++ks) {
      f16x8 b = *(const f16x8*)(bp + ks * 32);
      acc[nt] = __builtin_amdgcn_mfma_f32_16x16x32_f16(a1[ks], b, acc[nt], 0, 0, 0);
    }
  }
  // bias + LN stats (4 rows per lane)
  float ps[4] = {0, 0, 0, 0}, pq[4] = {0, 0, 0, 0};
#pragma unroll
  for (int nt = 0; nt < 16; ++nt) {
    float bb = bf[nt * 16 + myr];
#pragma unroll
    for (int r = 0; r < 4; ++r) {
      float v = acc[nt][r] + bb;
      acc[nt][r] = v;
      ps[r] += v; pq[r] += v * v;
    }
  }
#pragma unroll
  for (int o = 1; o < 16; o <<= 1) {
#pragma unroll
    for (int r = 0; r < 4; ++r) { ps[r] += __shfl_xor(ps[r], o); pq[r] += __shfl_xor(pq[r], o); }
  }
  float mu[4], rs[4];
#pragma unroll
  for (int r = 0; r < 4; ++r) {
    mu[r] = ps[r] * (1.f / 256.f);
    float var = pq[r] * (1.f / 256.f) - mu[r] * mu[r];
    rs[r] = rsqrtf(var + 1e-5f);
  }
  // normalize + relu + store h fp16 to swizzled LDS
#pragma unroll
  for (int nt = 0; nt < 16; ++nt) {
    int col = nt * 16 + myr;
    float g = lg[col], b2 = lb[col];
#pragma unroll
    for (int r = 0; r < 4; ++r) {
      int row = wv * 16 + (lane >> 4) * 4 + r;
      float v = (acc[nt][r] - mu[r]) * rs[r] * g + b2;
      v = fmaxf(v, 0.f);
      int byteoff = row * 512 + ((col * 2) ^ ((row & 7) << 4));
      *(f16*)((char*)hbuf + byteoff) = (f16)v;
    }
  }
  __syncthreads();
  // GEMM2
  f16x8 a2[8];
  {
    int row = wv * 16 + myr;
#pragma unroll
    for (int ks = 0; ks < 8; ++ks) {
      int byteoff = row * 512 + (((ks * 32 + dgrp) * 2) ^ ((row & 7) << 4));
      a2[ks] = *(const f16x8*)((char*)hbuf + byteoff);
    }
  }
  f32x4 acc2[16];
#pragma unroll
  for (int nt = 0; nt < 16; ++nt) acc2[nt] = (f32x4){0.f, 0.f, 0.f, 0.f};
#pragma unroll 1
  for (int nt = 0; nt < 16; ++nt) {
    const f16* bp = WoT + (nt * 16 + myr) * DDIM + dgrp;
#pragma unroll
    for (int ks = 0; ks < 8; ++ks) {
      f16x8 b = *(const f16x8*)(bp + ks * 32);
      acc2[nt] = __builtin_amdgcn_mfma_f32_16x16x32_f16(a2[ks], b, acc2[nt], 0, 0, 0);
    }
  }
#pragma unroll
  for (int nt = 0; nt < 16; ++nt) {
    int col = nt * 16 + myr;
    float bb = bo[col];
#pragma unroll
    for (int r = 0; r < 4; ++r) {
      int row = t0 + wv * 16 + (lane >> 4) * 4 + r;
      out[row * DDIM + col] = acc2[nt][r] + bb;
    }
  }
}

// ---------------- launcher ----------------
extern "C" void kernel_launch(void* const* d_in, const int* in_sizes, int n_in,
                              void* d_out, int out_size, void* d_ws, size_t ws_size,
                              hipStream_t stream)
{
  (void)in_sizes; (void)n_in; (void)out_size; (void)ws_size;
  const float* x  = (const float*)d_in[0];
  const float* mk = (const float*)d_in[1];
  const float* mv = (const float*)d_in[2];
  const float* Wf = (const float*)d_in[3];
  const float* bf = (const float*)d_in[4];
  const float* lg = (const float*)d_in[5];
  const float* lb = (const float*)d_in[6];
  const float* Wo = (const float*)d_in[7];
  const float* bo = (const float*)d_in[8];
  // top_k (d_in[9]) is the compile-time constant 32

  char* ws = (char*)d_ws;
  f16*  xh  = (f16*)ws;                               // 4 MB
  f16*  kh  = (f16*)(ws + (4u << 20));                // 8 MB
  f16*  WfT = (f16*)(ws + (12u << 20));               // 128 KB
  f16*  WoT = (f16*)(ws + (12u << 20) + (1u << 17));  // 128 KB
  float* pts = (float*)(ws + (12u << 20) + (1u << 18));            // 2 MB
  int*   pti = (int*)(ws + (12u << 20) + (1u << 18) + (1u << 21)); // 2 MB
  float* fused = (float*)d_out;   // d_out doubles as fused scratch

  prep_cvt<<<dim3(6144), dim3(256), 0, stream>>>(x, mk, xh, kh);
  prep_tr<<<dim3(512), dim3(256), 0, stream>>>(Wf, Wo, WfT, WoT);
  k1_topk<<<dim3(256), dim3(256), 0, stream>>>(xh, kh, pts, pti);
  k2_merge<<<dim3(2048), dim3(256), 0, stream>>>(pts, pti, x, mv, fused);
  k3_ffn<<<dim3(256), dim3(128), 0, stream>>>(fused, WfT, WoT, bf, lg, lb, bo, (float*)d_out);
}

// Round 2
// 250.920 us; speedup vs baseline: 12.7463x; 12.7463x over previous
//
#include <hip/hip_runtime.h>

typedef _Float16 f16;
typedef f16 f16x4 __attribute__((ext_vector_type(4)));
typedef f16 f16x8 __attribute__((ext_vector_type(8)));
typedef float f32x4 __attribute__((ext_vector_type(4)));
typedef float f32x16 __attribute__((ext_vector_type(16)));

#define NTOK 8192
#define DDIM 256
#define MKEY 16384
#define NPART 8
#define PKEYS 2048     // keys per part
#define CH   32        // keys per staged chunk
#define NCHK (PKEYS/CH)  // 64
#define LLOC 8         // per-lane top-L list

// ---------------- prep: f32 -> fp16 conversions ----------------
__global__ __launch_bounds__(256) void prep_cvt(const float* __restrict__ x,
                                                const float* __restrict__ mk,
                                                f16* __restrict__ xh, f16* __restrict__ kh)
{
  int i = blockIdx.x * 256 + threadIdx.x;
  const int NX4 = NTOK * DDIM / 4;
  if (i < NX4) {
    float4 v = ((const float4*)x)[i];
    f16x4 o = {(f16)v.x, (f16)v.y, (f16)v.z, (f16)v.w};
    ((f16x4*)xh)[i] = o;
  } else {
    int j = i - NX4;                       // < MKEY*DDIM/4
    float4 v = ((const float4*)mk)[j];
    f16x4 o = {(f16)v.x, (f16)v.y, (f16)v.z, (f16)v.w};
    ((f16x4*)kh)[j] = o;
  }
}

// transpose W [k][n] -> WT [n][k] in fp16 (both 256x256)
__global__ __launch_bounds__(256) void prep_tr(const float* __restrict__ Wf,
                                               const float* __restrict__ Wo,
                                               f16* __restrict__ WfT, f16* __restrict__ WoT)
{
  int i = blockIdx.x * 256 + threadIdx.x;  // 0..131071
  const float* W = Wf; f16* WT = WfT; int j = i;
  if (i >= 65536) { W = Wo; WT = WoT; j = i - 65536; }
  int n = j >> 8, k = j & 255;
  WT[j] = (f16)W[k * 256 + n];
}

// ---------------- K1: scores (32x32x16 MFMA, operand-swapped) + per-lane reg top-8 ----------------
// grid 512 = 64 token-blocks (128 tokens) x 8 key-parts (2048 keys). part = bid&7 -> one part per XCD L2.
__global__ __launch_bounds__(256, 2) void k1_topk(const f16* __restrict__ xh,
                                                  const f16* __restrict__ kh,
                                                  float* __restrict__ pt_s,
                                                  unsigned short* __restrict__ pt_i)
{
  __shared__ __align__(16) f16 kbuf[2][CH * DDIM];   // 2 x 16 KB, XOR-swizzled rows

  const int tid = threadIdx.x, lane = tid & 63, wv = tid >> 6;
  const int part = blockIdx.x & 7;
  const int tb   = blockIdx.x >> 3;
  const int t0   = tb * 128;
  const int key0 = part * PKEYS;
  const int tko  = lane & 31;        // token col owned by this lane
  const int hi   = lane >> 5;        // key-row half / k-half

  // token B-fragments: 32 tokens x 256 d resident in regs (64 VGPR)
  f16x8 bfr[16];
  {
    const f16* ap = xh + (t0 + wv * 32 + tko) * DDIM + hi * 8;
#pragma unroll
    for (int ks = 0; ks < 16; ++ks) bfr[ks] = *(const f16x8*)(ap + ks * 16);
  }

  // per-lane sorted (desc) top-8 of this lane's key substream
  float e[LLOC]; int ky[LLOC];
#pragma unroll
  for (int j = 0; j < LLOC; ++j) { e[j] = -1e30f; ky[j] = 0; }

  // stage one 32-key chunk; LDS dest linear, global source pre-swizzled so
  // lds[key*512 + (byte_d ^ ((key&7)<<4))] = kh[key][d]
  auto stage = [&](int buf, int c0) {
    const f16* base = kh + (key0 + c0) * DDIM;
#pragma unroll
    for (int is = 0; is < 4; ++is) {
      int o   = is * 4096 + tid * 16;
      int key = o >> 9;
      int d2  = (o & 511) ^ ((key & 7) << 4);
      const void* g = (const char*)(base + key * DDIM) + d2;
      void* l = (char*)(&kbuf[buf][0]) + is * 4096 + wv * 1024;  // wave-uniform base
      __builtin_amdgcn_global_load_lds((const __attribute__((address_space(1))) unsigned int*)g,
                                       (__attribute__((address_space(3))) unsigned int*)l,
                                       16, 0, 0);
    }
  };

  stage(0, 0);
  __syncthreads();

  for (int c = 0; c < NCHK; ++c) {
    const int buf = c & 1;
    if (c + 1 < NCHK) stage(buf ^ 1, (c + 1) * CH);   // async prefetch

    // ---- MFMA: A = 32 keys (LDS), B = 32 tokens (regs), K=256 in 16 steps ----
    f32x16 acc = {0.f,0.f,0.f,0.f,0.f,0.f,0.f,0.f,0.f,0.f,0.f,0.f,0.f,0.f,0.f,0.f};
    const char* kb = (const char*)&kbuf[buf][0];
#pragma unroll
    for (int ks = 0; ks < 16; ++ks) {
      int addr = tko * 512 + ((ks * 32 + hi * 16) ^ ((tko & 7) << 4));
      f16x8 a = *(const f16x8*)(kb + addr);
      acc = __builtin_amdgcn_mfma_f32_32x32x16_f16(a, bfr[ks], acc, 0, 0, 0);
    }

    // ---- selection: extract lane's candidates (max-tree) into sorted reg list ----
    float cnd[16];
#pragma unroll
    for (int r = 0; r < 16; ++r) cnd[r] = acc[r];
#pragma unroll 1
    for (;;) {
      float bv = cnd[0]; int bi = 0;
#pragma unroll
      for (int r = 1; r < 16; ++r) { bool g = cnd[r] > bv; bv = g ? cnd[r] : bv; bi = g ? r : bi; }
      if (!__any(bv > e[LLOC - 1])) break;
      if (bv > e[LLOC - 1]) {
        // C row = (reg&3) + 8*(reg>>2) + 4*hi  ->  key within part
        int key = c * CH + ((bi & 3) | ((bi & 12) << 1)) + hi * 4;
        float cs = bv; int ck = key;
#pragma unroll
        for (int j = 0; j < LLOC; ++j) {
          bool g = cs > e[j];
          float t1 = g ? cs : e[j]; float t2 = g ? e[j] : cs; e[j] = t1; cs = t2;
          int   u1 = g ? ck : ky[j]; int  u2 = g ? ky[j] : ck; ky[j] = u1; ck = u2;
        }
      }
#pragma unroll
      for (int r = 0; r < 16; ++r) cnd[r] = (r == bi) ? -1e30f : cnd[r];
    }
    __syncthreads();   // drains staging vmcnt + guards kbuf swap
  }

  // writeout: 16 entries per token per part (2 lanes x top-8)
  const int tok = t0 + wv * 32 + tko;
#pragma unroll
  for (int j = 0; j < LLOC; ++j) {
    pt_s[tok * 128 + part * 16 + hi * 8 + j] = e[j];
    pt_i[tok * 128 + part * 16 + hi * 8 + j] = (unsigned short)(key0 + ky[j]);
  }
}

// ---------------- K2: merge 128 partials, softmax, gather, fused = x + ctx ----------------
__global__ __launch_bounds__(256) void k2_merge(const float* __restrict__ pt_s,
                                                const unsigned short* __restrict__ pt_i,
                                                const float* __restrict__ x,
                                                const float* __restrict__ mv,
                                                float* __restrict__ fused)
{
  __shared__ float ws_[4][32];
  __shared__ int   is_[4][32];
  const int lane = threadIdx.x & 63, wv = threadIdx.x >> 6;
  const int tok = blockIdx.x * 4 + wv;
  const float* ps = pt_s + tok * 128;
  const unsigned short* pi = pt_i + tok * 128;
  float s0 = ps[lane], s1 = ps[64 + lane];
  int   i0 = pi[lane], i1 = pi[64 + lane];
  int r0 = 0, r1 = 0;
#pragma unroll 1
  for (int j = 0; j < 64; ++j) {
    float a0 = __shfl(s0, j), a1 = __shfl(s1, j);
    r0 += (a0 > s0) || (a0 == s0 && j < lane);
    r0 += (a1 > s0);
    r1 += (a0 > s1) || (a0 == s1);
    r1 += (a1 > s1) || (a1 == s1 && j < lane);
  }
  float m = fmaxf(s0, s1);
#pragma unroll
  for (int o = 32; o; o >>= 1) m = fmaxf(m, __shfl_xor(m, o));
  float e0 = (r0 < 32) ? __expf(s0 - m) : 0.f;
  float e1 = (r1 < 32) ? __expf(s1 - m) : 0.f;
  float sum = e0 + e1;
#pragma unroll
  for (int o = 32; o; o >>= 1) sum += __shfl_xor(sum, o);
  if (r0 < 32) { ws_[wv][r0] = e0 / sum; is_[wv][r0] = i0; }
  if (r1 < 32) { ws_[wv][r1] = e1 / sum; is_[wv][r1] = i1; }
  asm volatile("s_waitcnt lgkmcnt(0)" ::: "memory");
  const int d = lane * 4;
  float4 a = {0.f, 0.f, 0.f, 0.f};
#pragma unroll 4
  for (int k = 0; k < 32; ++k) {
    float w = ws_[wv][k]; int id = is_[wv][k];
    float4 v = *(const float4*)(mv + id * 256 + d);
    a.x += w * v.x; a.y += w * v.y; a.z += w * v.z; a.w += w * v.w;
  }
  float4 xv = *(const float4*)(x + tok * 256 + d);
  float4 o4 = {xv.x + a.x, xv.y + a.y, xv.z + a.z, xv.w + a.w};
  *(float4*)(fused + tok * 256 + d) = o4;
}

// ---------------- K3: fused GEMM1 -> LN -> ReLU -> GEMM2 ----------------
__global__ __launch_bounds__(128) void k3_ffn(const float* __restrict__ fused,
                                              const f16* __restrict__ WfT,
                                              const f16* __restrict__ WoT,
                                              const float* __restrict__ bf,
                                              const float* __restrict__ lg,
                                              const float* __restrict__ lb,
                                              const float* __restrict__ bo,
                                              float* __restrict__ out)
{
  __shared__ __align__(16) f16 hbuf[32 * DDIM];   // 16 KB, XOR-swizzled
  const int lane = threadIdx.x & 63, wv = threadIdx.x >> 6;
  const int t0 = blockIdx.x * 32;
  const int myr = lane & 15;
  const int dgrp = (lane >> 4) * 8;

  f16x8 a1[8];
  {
    const float* ap = fused + (t0 + wv * 16 + myr) * DDIM + dgrp;
#pragma unroll
    for (int ks = 0; ks < 8; ++ks) {
      float4 v0 = *(const float4*)(ap + ks * 32);
      float4 v1 = *(const float4*)(ap + ks * 32 + 4);
      f16x8 t = {(f16)v0.x, (f16)v0.y, (f16)v0.z, (f16)v0.w,
                 (f16)v1.x, (f16)v1.y, (f16)v1.z, (f16)v1.w};
      a1[ks] = t;
    }
  }
  f32x4 acc[16];
#pragma unroll
  for (int nt = 0; nt < 16; ++nt) acc[nt] = (f32x4){0.f, 0.f, 0.f, 0.f};
#pragma unroll 1
  for (int nt = 0; nt < 16; ++nt) {
    const f16* bp = WfT + (nt * 16 + myr) * DDIM + dgrp;
#pragma unroll
    for (int ks = 0; ks < 8; ++ks) {
      f16x8 b = *(const f16x8*)(bp + ks * 32);
      acc[nt] = __builtin_amdgcn_mfma_f32_16x16x32_f16(a1[ks], b, acc[nt], 0, 0, 0);
    }
  }
  float ps[4] = {0, 0, 0, 0}, pq[4] = {0, 0, 0, 0};
#pragma unroll
  for (int nt = 0; nt < 16; ++nt) {
    float bb = bf[nt * 16 + myr];
#pragma unroll
    for (int r = 0; r < 4; ++r) {
      float v = acc[nt][r] + bb;
      acc[nt][r] = v;
      ps[r] += v; pq[r] += v * v;
    }
  }
#pragma unroll
  for (int o = 1; o < 16; o <<= 1) {
#pragma unroll
    for (int r = 0; r < 4; ++r) { ps[r] += __shfl_xor(ps[r], o); pq[r] += __shfl_xor(pq[r], o); }
  }
  float mu[4], rs[4];
#pragma unroll
  for (int r = 0; r < 4; ++r) {
    mu[r] = ps[r] * (1.f / 256.f);
    float var = pq[r] * (1.f / 256.f) - mu[r] * mu[r];
    rs[r] = rsqrtf(var + 1e-5f);
  }
#pragma unroll
  for (int nt = 0; nt < 16; ++nt) {
    int col = nt * 16 + myr;
    float g = lg[col], b2 = lb[col];
#pragma unroll
    for (int r = 0; r < 4; ++r) {
      int row = wv * 16 + (lane >> 4) * 4 + r;
      float v = (acc[nt][r] - mu[r]) * rs[r] * g + b2;
      v = fmaxf(v, 0.f);
      int byteoff = row * 512 + ((col * 2) ^ ((row & 7) << 4));
      *(f16*)((char*)hbuf + byteoff) = (f16)v;
    }
  }
  __syncthreads();
  f16x8 a2[8];
  {
    int row = wv * 16 + myr;
#pragma unroll
    for (int ks = 0; ks < 8; ++ks) {
      int byteoff = row * 512 + (((ks * 32 + dgrp) * 2) ^ ((row & 7) << 4));
      a2[ks] = *(const f16x8*)((char*)hbuf + byteoff);
    }
  }
  f32x4 acc2[16];
#pragma unroll
  for (int nt = 0; nt < 16; ++nt) acc2[nt] = (f32x4){0.f, 0.f, 0.f, 0.f};
#pragma unroll 1
  for (int nt = 0; nt < 16; ++nt) {
    const f16* bp = WoT + (nt * 16 + myr) * DDIM + dgrp;
#pragma unroll
    for (int ks = 0; ks < 8; ++ks) {
      f16x8 b = *(const f16x8*)(bp + ks * 32);
      acc2[nt] = __builtin_amdgcn_mfma_f32_16x16x32_f16(a2[ks], b, acc2[nt], 0, 0, 0);
    }
  }
#pragma unroll
  for (int nt = 0; nt < 16; ++nt) {
    int col = nt * 16 + myr;
    float bb = bo[col];
#pragma unroll
    for (int r = 0; r < 4; ++r) {
      int row = t0 + wv * 16 + (lane >> 4) * 4 + r;
      out[row * DDIM + col] = acc2[nt][r] + bb;
    }
  }
}

// ---------------- launcher ----------------
extern "C" void kernel_launch(void* const* d_in, const int* in_sizes, int n_in,
                              void* d_out, int out_size, void* d_ws, size_t ws_size,
                              hipStream_t stream)
{
  (void)in_sizes; (void)n_in; (void)out_size; (void)ws_size;
  const float* x  = (const float*)d_in[0];
  const float* mk = (const float*)d_in[1];
  const float* mv = (const float*)d_in[2];
  const float* Wf = (const float*)d_in[3];
  const float* bf = (const float*)d_in[4];
  const float* lg = (const float*)d_in[5];
  const float* lb = (const float*)d_in[6];
  const float* Wo = (const float*)d_in[7];
  const float* bo = (const float*)d_in[8];

  char* ws = (char*)d_ws;
  f16*  xh  = (f16*)ws;                               // 4 MB
  f16*  kh  = (f16*)(ws + (4u << 20));                // 8 MB
  f16*  WfT = (f16*)(ws + (12u << 20));               // 128 KB
  f16*  WoT = (f16*)(ws + (12u << 20) + (1u << 17));  // 128 KB
  float*          pts = (float*)(ws + (13u << 20));           // 4 MB
  unsigned short* pti = (unsigned short*)(ws + (17u << 20));  // 2 MB
  float* fused = (float*)d_out;   // d_out doubles as fused scratch

  prep_cvt<<<dim3(6144), dim3(256), 0, stream>>>(x, mk, xh, kh);
  prep_tr<<<dim3(512), dim3(256), 0, stream>>>(Wf, Wo, WfT, WoT);
  k1_topk<<<dim3(512), dim3(256), 0, stream>>>(xh, kh, pts, pti);
  k2_merge<<<dim3(2048), dim3(256), 0, stream>>>(pts, pti, x, mv, fused);
  k3_ffn<<<dim3(256), dim3(128), 0, stream>>>(fused, WfT, WoT, bf, lg, lb, bo, (float*)d_out);
}